// Round 20
// baseline (449.447 us; speedup 1.0000x reference)
//
#include <hip/hip_runtime.h>
#include <hip/hip_bf16.h>
#include <math.h>

#define NVEC 2000
#define DD   768
#define HH   1024
#define KNUM 250
#define MSEL 400
#define MR   399     // m-1 rows
#define OUTW 251
#define PPAD 256                 // padded antecedents per anaphor
#define NPAIR (MR * PPAD)        // 102144 padded pair rows
#define BM 128
#define BN 256
#define BK 64
#define NKT (DD / BK)            // 12
#define NNB (HH / BN)            // 4
#define KH1 271                  // khalf=1 blocks exist only for i < 271 (else fully masked)
#define PAIRBLKS (MR + KH1)      // 670

typedef short  bf16x8 __attribute__((ext_vector_type(8)));
typedef float  f32x4  __attribute__((ext_vector_type(4)));
typedef unsigned int u32;
typedef u32    u32x4  __attribute__((ext_vector_type(4)));

__device__ __forceinline__ float waveSum(float p) {
#pragma unroll
  for (int off = 32; off >= 1; off >>= 1) p += __shfl_xor(p, off, 64);
  return p;
}
__device__ __forceinline__ float waveMax(float p) {
#pragma unroll
  for (int off = 32; off >= 1; off >>= 1) p = fmaxf(p, __shfl_xor(p, off, 64));
  return p;
}
__device__ __forceinline__ short f2bf(float f) {
  __hip_bfloat16 h = __float2bfloat16(f);     // RNE; pairs fuse to v_cvt_pk_bf16_f32
  return __builtin_bit_cast(short, h);
}
__device__ __forceinline__ void gload_lds16(const void* g, void* l) {
  __builtin_amdgcn_global_load_lds(
      (const __attribute__((address_space(1))) u32*)g,
      (__attribute__((address_space(3))) u32*)l, 16, 0, 0);
}
// x[e] = bf16( av[e] * f32(b[e]) )  -- 8-element chunk, in registers
__device__ __forceinline__ bf16x8 prodcvt(const float* av, bf16x8 b) {
  u32x4 u = __builtin_bit_cast(u32x4, b);
  bf16x8 r;
#pragma unroll
  for (int p = 0; p < 4; ++p) {
    const float blo = __builtin_bit_cast(float, u[p] << 16);
    const float bhi = __builtin_bit_cast(float, u[p] & 0xffff0000u);
    r[2 * p]     = f2bf(av[2 * p]     * blo);
    r[2 * p + 1] = f2bf(av[2 * p + 1] * bhi);
  }
  return r;
}

// ---------------- K1: score partials, 16 rows x H-half per block (grid 125x2) ----------------
// spart[row][half] = sum over that half's 512 cols of relu(v@Wm1+bm1)*wm2.
// Halves combined (+bm2) in the sort kernel: 2 addends, fixed order -> deterministic.
__global__ __launch_bounds__(512) void scores_kernel(
    const float* __restrict__ vectors, const float* __restrict__ Wm1,
    const float* __restrict__ bm1, const float* __restrict__ wm2,
    float* __restrict__ spart) {
  __shared__ float vrow[16 * DD];      // 48 KB
  __shared__ float red[8];
  const int tid = threadIdx.x;
  const int base = blockIdx.x * 16;
  const int half = blockIdx.y;
  for (int idx = tid; idx < 16 * DD; idx += 512)
    vrow[idx] = vectors[base * DD + idx];
  __syncthreads();
  float acc[16];
#pragma unroll
  for (int r = 0; r < 16; ++r) acc[r] = 0.f;
  const float* W = Wm1 + half * 512 + tid;
#pragma unroll 4
  for (int d = 0; d < DD; ++d) {
    const float w = W[(size_t)d * HH];
#pragma unroll
    for (int r = 0; r < 16; ++r) acc[r] += vrow[r * DD + d] * w;
  }
  const float b = bm1[half * 512 + tid];
  const float m = wm2[half * 512 + tid];
  for (int r = 0; r < 16; ++r) {
    float p = fmaxf(acc[r] + b, 0.f) * m;
    p = waveSum(p);
    if ((tid & 63) == 0) red[tid >> 6] = p;
    __syncthreads();
    if (tid == 0) {
      float t = red[0];
#pragma unroll
      for (int w8 = 1; w8 < 8; ++w8) t += red[w8];
      spart[(size_t)(base + r) * 2 + half] = t;
    }
    __syncthreads();
  }
}

// ---------------- K2 (fused): block 0 = sort+lexsort | blocks 1..192 = Wt transpose ----------------
__global__ __launch_bounds__(1024) void sortwt_kernel(
    const float* __restrict__ spart, const int* __restrict__ sst,
    const int* __restrict__ sen, const float* __restrict__ bm2,
    const float* __restrict__ Wp1,
    int* __restrict__ perm, float* __restrict__ sfin, ushort* __restrict__ Wt) {
  const int tid = threadIdx.x;
  if (blockIdx.x == 0) {
    __shared__ float ks[2048];
    __shared__ int   ki[2048];
    __shared__ int s_st[512], s_en[512], s_j[512];
    const float bm2v = bm2[0];
    for (int e = tid; e < 2048; e += 1024) {
      ks[e] = (e < NVEC) ? (spart[(size_t)e * 2] + spart[(size_t)e * 2 + 1] + bm2v)
                         : -INFINITY;
      ki[e] = e;
    }
    __syncthreads();
    for (int k = 2; k <= 2048; k <<= 1) {
      for (int j = k >> 1; j > 0; j >>= 1) {
        for (int e = tid; e < 2048; e += 1024) {
          const int l = e ^ j;
          if (l > e) {
            const float s1 = ks[e], s2 = ks[l];
            const int i1 = ki[e], i2 = ki[l];
            const bool first = (s1 > s2) || (s1 == s2 && i1 < i2);
            const bool up = ((e & k) == 0);
            if (up ? !first : first) {
              ks[e] = s2; ks[l] = s1; ki[e] = i2; ki[l] = i1;
            }
          }
        }
        __syncthreads();
      }
    }
    for (int e = tid; e < 512; e += 1024) {
      if (e < MSEL) { const int ti = ki[e]; s_st[e] = sst[ti]; s_en[e] = sen[ti]; }
      else { s_st[e] = 0x7fffffff; s_en[e] = 0x7fffffff; }
      s_j[e] = e;
    }
    __syncthreads();
    for (int k = 2; k <= 512; k <<= 1) {
      for (int j = k >> 1; j > 0; j >>= 1) {
        for (int e = tid; e < 512; e += 1024) {
          const int l = e ^ j;
          if (l > e) {
            const int a0 = s_st[e], a1 = s_en[e], a2 = s_j[e];
            const int b0 = s_st[l], b1 = s_en[l], b2 = s_j[l];
            const bool first = (a0 < b0) || (a0 == b0 && (a1 < b1 || (a1 == b1 && a2 < b2)));
            const bool up = ((e & k) == 0);
            if (up ? !first : first) {
              s_st[e] = b0; s_en[e] = b1; s_j[e] = b2;
              s_st[l] = a0; s_en[l] = a1; s_j[l] = a2;
            }
          }
        }
        __syncthreads();
      }
    }
    for (int i = tid; i < MSEL; i += 1024) {
      const int src = s_j[MSEL - 1 - i];
      const int vi = ki[src];
      perm[i] = vi;
      sfin[i] = spart[(size_t)vi * 2] + spart[(size_t)vi * 2 + 1] + bm2v;
    }
  } else {
    // ---- Wt transpose tile: Wt[n][k] = bf16(Wab[k][n]) ----
    __shared__ float tile[64][65];
    const int t2 = blockIdx.x - 1;            // 0..191
    const int kb = t2 % 12;
    const int nb = t2 / 12;
    const float* Wab = Wp1 + 2 * DD * HH;
    for (int idx = tid; idx < 64 * 64; idx += 1024) {
      const int kk = idx >> 6, nn = idx & 63;
      tile[kk][nn] = Wab[(size_t)(kb * 64 + kk) * HH + nb * 64 + nn];
    }
    __syncthreads();
    for (int idx = tid; idx < 64 * 64; idx += 1024) {
      const int nn = idx >> 6, kk = idx & 63;
      Wt[(size_t)(nb * 64 + nn) * DD + kb * 64 + kk] = (ushort)f2bf(tile[kk][nn]);
    }
  }
}

// ---------------- K3: Ha = v@Wa, Hv = v@Wb; gather Vp/Vpb; zero done[] ----------------
__global__ __launch_bounds__(512) void hab_kernel(
    const float* __restrict__ vectors, const float* __restrict__ Wp1,
    const int* __restrict__ perm, float* __restrict__ Ha, float* __restrict__ Hv,
    float* __restrict__ Vp, ushort* __restrict__ Vpb, int* __restrict__ done) {
  __shared__ float vrow[8 * DD];
  const int tid = threadIdx.x;
  const int base = blockIdx.x * 8;
  const int mat = blockIdx.y >> 1;       // 0 = Wa, 1 = Wb
  const int half = blockIdx.y & 1;       // col half
  if (blockIdx.x == 0 && blockIdx.y == 0 && tid < MR) done[tid] = 0;
  for (int r = 0; r < 8; ++r) {
    const int pi = perm[base + r];
    for (int d = tid; d < DD; d += 512) {
      const float val = vectors[pi * DD + d];
      vrow[r * DD + d] = val;
      if (blockIdx.y == 0) {
        Vp[(size_t)(base + r) * DD + d] = val;
        Vpb[(size_t)(base + r) * DD + d] = (ushort)f2bf(val);
      }
    }
  }
  __syncthreads();
  float acc[8];
#pragma unroll
  for (int r = 0; r < 8; ++r) acc[r] = 0.f;
  const float* W = Wp1 + (size_t)mat * DD * HH + half * 512 + tid;
#pragma unroll 4
  for (int d = 0; d < DD; ++d) {
    const float w = W[(size_t)d * HH];
#pragma unroll
    for (int r = 0; r < 8; ++r) acc[r] += vrow[r * DD + d] * w;
  }
  float* dst = mat ? Hv : Ha;
  for (int r = 0; r < 8; ++r) {
    const int row = base + r;
    if (mat == 0 && row >= MR) continue;
    dst[(size_t)row * HH + half * 512 + tid] = acc[r];
  }
}

// ---------------- K4: pairwise einsum GEMM + fused last-block softmax ----------------
// Partials to distinct pp slots; __syncthreads (drain) -> tid0 __threadfence (device
// L2 writeback) -> atomicAdd(done[i]). Last contributing block (tgt = 8 if i<271 else 4)
// acquires and computes row i's softmax. Deterministic: complete fixed slot set, fixed
// reduction order, executor identity irrelevant.
__global__ __launch_bounds__(512, 2) void pair_kernel(
    const float* __restrict__ Vp, const ushort* __restrict__ Vpb,
    const ushort* __restrict__ Wt,
    const float* __restrict__ bp1, const float* __restrict__ wp2,
    const float* __restrict__ Ha, const float* __restrict__ Hv,
    const float* __restrict__ sfin, const float* __restrict__ bp2,
    float* __restrict__ pp, int* __restrict__ done, float* __restrict__ out) {
  __shared__ __align__(16) ushort As[BM * BK];      // 16 KB
  __shared__ __align__(16) ushort Bs[BN * BK];      // 32 KB
  __shared__ float redp[BM][4];                     // 2 KB
  __shared__ float sred[8];
  __shared__ int sdone;
  const int tid = threadIdx.x;
  const int bx = blockIdx.x;          // 0..669
  const int khalf = (bx < MR) ? 0 : 1;
  const int i = (bx < MR) ? bx : (bx - MR);
  const int nb = blockIdx.y;          // 0..3
  const int n0 = nb * BN;
  const int lane = tid & 63;
  const int wid = tid >> 6;           // 0..7
  const int wr = wid >> 2, wc = wid & 3;
  const int lhi = lane >> 4, llo = lane & 15;

  // ---- stage geometry ----
  const int cs = tid & 7;
  const int rb9 = tid >> 3;                   // 0..63
  const int csx = cs ^ (rb9 & 7);             // same for both A chunks
  const ushort* vsrc[2];
  int rowA[2];
#pragma unroll
  for (int it = 0; it < 2; ++it) {
    rowA[it] = it * 64 + rb9;                 // 0..127
    int j = i + 1 + khalf * BM + rowA[it];
    if (j > MR) j = MR;
    vsrc[it] = Vpb + (size_t)j * DD + cs * 8;
  }
  int rowB[4];
#pragma unroll
  for (int it = 0; it < 4; ++it) rowB[it] = it * 64 + rb9;   // 0..255
  const float* avp = Vp + (size_t)i * DD + cs * 8;   // L1-hot row i

  f32x4 acc[4][4];
#pragma unroll
  for (int a = 0; a < 4; ++a)
#pragma unroll
    for (int b = 0; b < 4; ++b) acc[a][b] = (f32x4){0.f, 0.f, 0.f, 0.f};

  for (int kt = 0; kt < NKT; ++kt) {
    const int kg = kt * BK;
    // ---- stage phase: A-src loads FIRST (oldest VMEM), then B-DMAs, then prodcvt ----
    bf16x8 bv[2];
    float av[8];
#pragma unroll
    for (int it = 0; it < 2; ++it) bv[it] = *(const bf16x8*)(vsrc[it] + kg);
    *(float4*)(av) = *(const float4*)(avp + kg);
    *(float4*)(av + 4) = *(const float4*)(avp + kg + 4);
#pragma unroll
    for (int it = 0; it < 4; ++it)
      gload_lds16(Wt + (size_t)(n0 + rowB[it]) * DD + kg + csx * 8,
                  (char*)Bs + (it * 512 + tid) * 16);
#pragma unroll
    for (int it = 0; it < 2; ++it)
      *(bf16x8*)((char*)As + rowA[it] * 128 + (csx << 4)) = prodcvt(av, bv[it]);
    __syncthreads();   // drains DMA writes + A ds_writes
    // ---- compute phase: 2 k-steps of 32; 4x4 fragments per wave ----
#pragma unroll
    for (int ks = 0; ks < 2; ++ks) {
      bf16x8 af[4], bfr[4];
#pragma unroll
      for (int mi = 0; mi < 4; ++mi) {
        const int row = wr * 64 + mi * 16 + llo;
        const int ch = (ks * 4 + lhi) ^ (row & 7);
        af[mi] = *(const bf16x8*)((const char*)As + row * 128 + (ch << 4));
      }
#pragma unroll
      for (int ni = 0; ni < 4; ++ni) {
        const int row = wc * 64 + ni * 16 + llo;
        const int ch = (ks * 4 + lhi) ^ (row & 7);
        bfr[ni] = *(const bf16x8*)((const char*)Bs + row * 128 + (ch << 4));
      }
#pragma unroll
      for (int mi = 0; mi < 4; ++mi)
#pragma unroll
        for (int ni = 0; ni < 4; ++ni)
          acc[mi][ni] = __builtin_amdgcn_mfma_f32_16x16x32_bf16(af[mi], bfr[ni], acc[mi][ni], 0, 0, 0);
    }
    __syncthreads();   // all reads done before next stage overwrites
  }

  // ---- epilogue: relu(acc + Ha_i + Hv_j + bp1) . wp2 over this wave's 64 cols ----
  float hb4[4], wpv[4];
  int cg[4];
#pragma unroll
  for (int ni = 0; ni < 4; ++ni) {
    const int col = n0 + wc * 64 + ni * 16 + llo;
    cg[ni] = col;
    hb4[ni] = Ha[(size_t)i * HH + col] + bp1[col];
    wpv[ni] = wp2[col];
  }
#pragma unroll
  for (int mi = 0; mi < 4; ++mi) {
#pragma unroll
    for (int r = 0; r < 4; ++r) {
      const int rowl = wr * 64 + mi * 16 + lhi * 4 + r;
      int j = i + 1 + khalf * BM + rowl;
      if (j > MR) j = MR;
      float part = 0.f;
#pragma unroll
      for (int ni = 0; ni < 4; ++ni) {
        const float pre = acc[mi][ni][r] + hb4[ni] + Hv[(size_t)j * HH + cg[ni]];
        part += fmaxf(pre, 0.f) * wpv[ni];
      }
      part += __shfl_xor(part, 1, 64);
      part += __shfl_xor(part, 2, 64);
      part += __shfl_xor(part, 4, 64);
      part += __shfl_xor(part, 8, 64);
      if (llo == 0) redp[rowl][wc] = part;   // per-wave column-quarter partial
    }
  }
  __syncthreads();
  if (tid < BM)
    pp[(size_t)nb * NPAIR + (size_t)i * PPAD + khalf * BM + tid] =
        redp[tid][0] + redp[tid][1] + redp[tid][2] + redp[tid][3];

  // ---- completion protocol + fused softmax (last contributing block) ----
  __syncthreads();                       // all pp stores drained (barrier waits vmcnt 0)
  if (tid == 0) {
    __threadfence();                     // device-scope release (L2 writeback)
    sdone = atomicAdd(&done[i], 1);
  }
  __syncthreads();
  const int tgt = (i < KH1) ? 8 : 4;
  if (sdone == tgt - 1) {
    __threadfence();                     // acquire
    float v;
    if (tid < KNUM) {
      const int jidx = i + 1 + tid;
      const bool valid = jidx < MSEL;
      const int jc = valid ? jidx : MR;
      float s = 0.f;
#pragma unroll
      for (int b = 0; b < NNB; ++b) s += pp[(size_t)b * NPAIR + (size_t)i * PPAD + tid];
      v = valid ? (s + bp2[0] + sfin[jc] + sfin[i]) : -INFINITY;
    } else if (tid == KNUM) v = 0.f;
    else v = -INFINITY;
    float mx = waveMax(v);
    if ((tid & 63) == 0) sred[tid >> 6] = mx;
    __syncthreads();
    float m = sred[0];
#pragma unroll
    for (int w8 = 1; w8 < 8; ++w8) m = fmaxf(m, sred[w8]);
    __syncthreads();
    const float e = (tid <= KNUM) ? expf(v - m) : 0.f;
    float s2 = waveSum(e);
    if ((tid & 63) == 0) sred[tid >> 6] = s2;
    __syncthreads();
    float tot = sred[0];
#pragma unroll
    for (int w8 = 1; w8 < 8; ++w8) tot += sred[w8];
    if (tid <= KNUM) out[(size_t)i * OUTW + tid] = e / tot;
  }
}

extern "C" void kernel_launch(void* const* d_in, const int* in_sizes, int n_in,
                              void* d_out, int out_size, void* d_ws, size_t ws_size,
                              hipStream_t stream) {
  const float* vectors = (const float*)d_in[0];
  const float* Wm1 = (const float*)d_in[1];
  const float* bm1 = (const float*)d_in[2];
  const float* wm2 = (const float*)d_in[3];
  const float* bm2 = (const float*)d_in[4];
  const float* Wp1 = (const float*)d_in[5];
  const float* bp1 = (const float*)d_in[6];
  const float* wp2 = (const float*)d_in[7];
  const float* bp2 = (const float*)d_in[8];
  const int* sst = (const int*)d_in[9];
  const int* sen = (const int*)d_in[10];
  float* out = (float*)d_out;
  char* ws = (char*)d_ws;

  float* spart = (float*)(ws);                           // 2000*2 f32
  int*   perm  = (int*)(ws + 16384);                     // 400 i32
  float* sfin  = (float*)(ws + 18432);                   // 400 f32
  float* Ha    = (float*)(ws + 20480);                   // 400*1024 f32
  float* Hv    = (float*)(ws + 1658880);                 // 400*1024 f32
  float* Vp    = (float*)(ws + 3297280);                 // 400*768 f32
  ushort* Wt   = (ushort*)(ws + 4526080);                // 1024*768 bf16
  ushort* Vpb  = (ushort*)(ws + 6098944);                // 400*768 bf16
  float* pp    = (float*)(ws + 6713344);                 // 4 * 102144 f32 partials
  int*   done  = (int*)(ws + 8347648);                   // 399 i32 completion counters

  scores_kernel<<<dim3(125, 2), 512, 0, stream>>>(vectors, Wm1, bm1, wm2, spart);
  sortwt_kernel<<<193, 1024, 0, stream>>>(spart, sst, sen, bm2, Wp1, perm, sfin, Wt);
  hab_kernel<<<dim3(MSEL / 8, 4), 512, 0, stream>>>(vectors, Wp1, perm, Ha, Hv, Vp, Vpb, done);
  pair_kernel<<<dim3(PAIRBLKS, NNB), 512, 0, stream>>>(
      Vp, Vpb, Wt, bp1, wp2, Ha, Hv, sfin, bp2, pp, done, out);
}

// Round 21
// 372.368 us; speedup vs baseline: 1.2070x; 1.2070x over previous
//
#include <hip/hip_runtime.h>
#include <hip/hip_bf16.h>
#include <math.h>

#define NVEC 2000
#define DD   768
#define HH   1024
#define KNUM 250
#define MSEL 400
#define MR   399     // m-1 rows
#define OUTW 251
#define PPAD 256                 // padded antecedents per anaphor
#define NPAIR (MR * PPAD)        // 102144 padded pair rows
#define BM 128
#define BN 256
#define BK 64
#define NKT (DD / BK)            // 12
#define NNB (HH / BN)            // 4
#define KH1 271                  // khalf=1 blocks exist only for i < 271 (else fully masked)
#define PAIRBLKS (MR + KH1)      // 670

typedef short  bf16x8 __attribute__((ext_vector_type(8)));
typedef float  f32x4  __attribute__((ext_vector_type(4)));
typedef unsigned int u32;
typedef u32    u32x4  __attribute__((ext_vector_type(4)));

__device__ __forceinline__ float waveSum(float p) {
#pragma unroll
  for (int off = 32; off >= 1; off >>= 1) p += __shfl_xor(p, off, 64);
  return p;
}
__device__ __forceinline__ float waveMax(float p) {
#pragma unroll
  for (int off = 32; off >= 1; off >>= 1) p = fmaxf(p, __shfl_xor(p, off, 64));
  return p;
}
__device__ __forceinline__ short f2bf(float f) {
  __hip_bfloat16 h = __float2bfloat16(f);     // RNE; pairs fuse to v_cvt_pk_bf16_f32
  return __builtin_bit_cast(short, h);
}
__device__ __forceinline__ void gload_lds16(const void* g, void* l) {
  __builtin_amdgcn_global_load_lds(
      (const __attribute__((address_space(1))) u32*)g,
      (__attribute__((address_space(3))) u32*)l, 16, 0, 0);
}
// x[e] = bf16( av[e] * f32(b[e]) )  -- 8-element chunk, in registers
__device__ __forceinline__ bf16x8 prodcvt(const float* av, bf16x8 b) {
  u32x4 u = __builtin_bit_cast(u32x4, b);
  bf16x8 r;
#pragma unroll
  for (int p = 0; p < 4; ++p) {
    const float blo = __builtin_bit_cast(float, u[p] << 16);
    const float bhi = __builtin_bit_cast(float, u[p] & 0xffff0000u);
    r[2 * p]     = f2bf(av[2 * p]     * blo);
    r[2 * p + 1] = f2bf(av[2 * p + 1] * bhi);
  }
  return r;
}

// ---------------- K1: score partials, 16 rows x H-half per block (grid 125x2) ----------------
// spart[row][half]; halves combined (+bm2) in sort: 2 addends, fixed order -> deterministic.
__global__ __launch_bounds__(512) void scores_kernel(
    const float* __restrict__ vectors, const float* __restrict__ Wm1,
    const float* __restrict__ bm1, const float* __restrict__ wm2,
    float* __restrict__ spart) {
  __shared__ float vrow[16 * DD];      // 48 KB
  __shared__ float red[8];
  const int tid = threadIdx.x;
  const int base = blockIdx.x * 16;
  const int half = blockIdx.y;
  for (int idx = tid; idx < 16 * DD; idx += 512)
    vrow[idx] = vectors[base * DD + idx];
  __syncthreads();
  float acc[16];
#pragma unroll
  for (int r = 0; r < 16; ++r) acc[r] = 0.f;
  const float* W = Wm1 + half * 512 + tid;
#pragma unroll 4
  for (int d = 0; d < DD; ++d) {
    const float w = W[(size_t)d * HH];
#pragma unroll
    for (int r = 0; r < 16; ++r) acc[r] += vrow[r * DD + d] * w;
  }
  const float b = bm1[half * 512 + tid];
  const float m = wm2[half * 512 + tid];
  for (int r = 0; r < 16; ++r) {
    float p = fmaxf(acc[r] + b, 0.f) * m;
    p = waveSum(p);
    if ((tid & 63) == 0) red[tid >> 6] = p;
    __syncthreads();
    if (tid == 0) {
      float t = red[0];
#pragma unroll
      for (int w8 = 1; w8 < 8; ++w8) t += red[w8];
      spart[(size_t)(base + r) * 2 + half] = t;
    }
    __syncthreads();
  }
}

// ---------------- K2 (fused): block 0 = sort+lexsort | blocks 1..192 = Wt transpose ----------------
__global__ __launch_bounds__(1024) void sortwt_kernel(
    const float* __restrict__ spart, const int* __restrict__ sst,
    const int* __restrict__ sen, const float* __restrict__ bm2,
    const float* __restrict__ Wp1,
    int* __restrict__ perm, float* __restrict__ sfin, ushort* __restrict__ Wt) {
  const int tid = threadIdx.x;
  if (blockIdx.x == 0) {
    __shared__ float ks[2048];
    __shared__ int   ki[2048];
    __shared__ int s_st[512], s_en[512], s_j[512];
    const float bm2v = bm2[0];
    for (int e = tid; e < 2048; e += 1024) {
      ks[e] = (e < NVEC) ? (spart[(size_t)e * 2] + spart[(size_t)e * 2 + 1] + bm2v)
                         : -INFINITY;
      ki[e] = e;
    }
    __syncthreads();
    for (int k = 2; k <= 2048; k <<= 1) {
      for (int j = k >> 1; j > 0; j >>= 1) {
        for (int e = tid; e < 2048; e += 1024) {
          const int l = e ^ j;
          if (l > e) {
            const float s1 = ks[e], s2 = ks[l];
            const int i1 = ki[e], i2 = ki[l];
            const bool first = (s1 > s2) || (s1 == s2 && i1 < i2);
            const bool up = ((e & k) == 0);
            if (up ? !first : first) {
              ks[e] = s2; ks[l] = s1; ki[e] = i2; ki[l] = i1;
            }
          }
        }
        __syncthreads();
      }
    }
    for (int e = tid; e < 512; e += 1024) {
      if (e < MSEL) { const int ti = ki[e]; s_st[e] = sst[ti]; s_en[e] = sen[ti]; }
      else { s_st[e] = 0x7fffffff; s_en[e] = 0x7fffffff; }
      s_j[e] = e;
    }
    __syncthreads();
    for (int k = 2; k <= 512; k <<= 1) {
      for (int j = k >> 1; j > 0; j >>= 1) {
        for (int e = tid; e < 512; e += 1024) {
          const int l = e ^ j;
          if (l > e) {
            const int a0 = s_st[e], a1 = s_en[e], a2 = s_j[e];
            const int b0 = s_st[l], b1 = s_en[l], b2 = s_j[l];
            const bool first = (a0 < b0) || (a0 == b0 && (a1 < b1 || (a1 == b1 && a2 < b2)));
            const bool up = ((e & k) == 0);
            if (up ? !first : first) {
              s_st[e] = b0; s_en[e] = b1; s_j[e] = b2;
              s_st[l] = a0; s_en[l] = a1; s_j[l] = a2;
            }
          }
        }
        __syncthreads();
      }
    }
    for (int i = tid; i < MSEL; i += 1024) {
      const int src = s_j[MSEL - 1 - i];
      const int vi = ki[src];
      perm[i] = vi;
      sfin[i] = spart[(size_t)vi * 2] + spart[(size_t)vi * 2 + 1] + bm2v;
    }
  } else {
    // ---- Wt transpose tile: Wt[n][k] = bf16(Wab[k][n]) ----
    __shared__ float tile[64][65];
    const int t2 = blockIdx.x - 1;            // 0..191
    const int kb = t2 % 12;
    const int nb = t2 / 12;
    const float* Wab = Wp1 + 2 * DD * HH;
    for (int idx = tid; idx < 64 * 64; idx += 1024) {
      const int kk = idx >> 6, nn = idx & 63;
      tile[kk][nn] = Wab[(size_t)(kb * 64 + kk) * HH + nb * 64 + nn];
    }
    __syncthreads();
    for (int idx = tid; idx < 64 * 64; idx += 1024) {
      const int nn = idx >> 6, kk = idx & 63;
      Wt[(size_t)(nb * 64 + nn) * DD + kb * 64 + kk] = (ushort)f2bf(tile[kk][nn]);
    }
  }
}

// ---------------- K3: Ha = v@Wa, Hv = v@Wb; gather Vp (f32) + Vpb (bf16) ----------------
__global__ __launch_bounds__(512) void hab_kernel(
    const float* __restrict__ vectors, const float* __restrict__ Wp1,
    const int* __restrict__ perm, float* __restrict__ Ha, float* __restrict__ Hv,
    float* __restrict__ Vp, ushort* __restrict__ Vpb) {
  __shared__ float vrow[8 * DD];
  const int tid = threadIdx.x;
  const int base = blockIdx.x * 8;
  const int mat = blockIdx.y >> 1;       // 0 = Wa, 1 = Wb
  const int half = blockIdx.y & 1;       // col half
  for (int r = 0; r < 8; ++r) {
    const int pi = perm[base + r];
    for (int d = tid; d < DD; d += 512) {
      const float val = vectors[pi * DD + d];
      vrow[r * DD + d] = val;
      if (blockIdx.y == 0) {
        Vp[(size_t)(base + r) * DD + d] = val;
        Vpb[(size_t)(base + r) * DD + d] = (ushort)f2bf(val);
      }
    }
  }
  __syncthreads();
  float acc[8];
#pragma unroll
  for (int r = 0; r < 8; ++r) acc[r] = 0.f;
  const float* W = Wp1 + (size_t)mat * DD * HH + half * 512 + tid;
#pragma unroll 4
  for (int d = 0; d < DD; ++d) {
    const float w = W[(size_t)d * HH];
#pragma unroll
    for (int r = 0; r < 8; ++r) acc[r] += vrow[r * DD + d] * w;
  }
  float* dst = mat ? Hv : Ha;
  for (int r = 0; r < 8; ++r) {
    const int row = base + r;
    if (mat == 0 && row >= MR) continue;
    dst[(size_t)row * HH + half * 512 + tid] = acc[r];
  }
}

// ---------------- K4: pairwise einsum GEMM, 128x256 tile (r19 verbatim, best measured) ----------------
__global__ __launch_bounds__(512, 2) void pair_kernel(
    const float* __restrict__ Vp, const ushort* __restrict__ Vpb,
    const ushort* __restrict__ Wt,
    const float* __restrict__ bp1, const float* __restrict__ wp2,
    const float* __restrict__ Ha, const float* __restrict__ Hv,
    float* __restrict__ pp) {
  __shared__ __align__(16) ushort As[BM * BK];      // 16 KB
  __shared__ __align__(16) ushort Bs[BN * BK];      // 32 KB
  __shared__ float redp[BM][4];                     // 2 KB
  const int tid = threadIdx.x;
  const int bx = blockIdx.x;          // 0..669
  const int khalf = (bx < MR) ? 0 : 1;
  const int i = (bx < MR) ? bx : (bx - MR);
  const int nb = blockIdx.y;          // 0..3
  const int n0 = nb * BN;
  const int lane = tid & 63;
  const int wid = tid >> 6;           // 0..7
  const int wr = wid >> 2, wc = wid & 3;
  const int lhi = lane >> 4, llo = lane & 15;

  // ---- stage geometry ----
  const int cs = tid & 7;
  const int rb9 = tid >> 3;                   // 0..63
  const int csx = cs ^ (rb9 & 7);             // same for both A chunks
  const ushort* vsrc[2];
  int rowA[2];
#pragma unroll
  for (int it = 0; it < 2; ++it) {
    rowA[it] = it * 64 + rb9;                 // 0..127
    int j = i + 1 + khalf * BM + rowA[it];
    if (j > MR) j = MR;
    vsrc[it] = Vpb + (size_t)j * DD + cs * 8;
  }
  int rowB[4];
#pragma unroll
  for (int it = 0; it < 4; ++it) rowB[it] = it * 64 + rb9;   // 0..255
  const float* avp = Vp + (size_t)i * DD + cs * 8;   // L1-hot row i

  f32x4 acc[4][4];
#pragma unroll
  for (int a = 0; a < 4; ++a)
#pragma unroll
    for (int b = 0; b < 4; ++b) acc[a][b] = (f32x4){0.f, 0.f, 0.f, 0.f};

  for (int kt = 0; kt < NKT; ++kt) {
    const int kg = kt * BK;
    // ---- stage phase: A-src loads FIRST (oldest VMEM), then B-DMAs, then prodcvt ----
    bf16x8 bv[2];
    float av[8];
#pragma unroll
    for (int it = 0; it < 2; ++it) bv[it] = *(const bf16x8*)(vsrc[it] + kg);
    *(float4*)(av) = *(const float4*)(avp + kg);
    *(float4*)(av + 4) = *(const float4*)(avp + kg + 4);
#pragma unroll
    for (int it = 0; it < 4; ++it)
      gload_lds16(Wt + (size_t)(n0 + rowB[it]) * DD + kg + csx * 8,
                  (char*)Bs + (it * 512 + tid) * 16);
#pragma unroll
    for (int it = 0; it < 2; ++it)
      *(bf16x8*)((char*)As + rowA[it] * 128 + (csx << 4)) = prodcvt(av, bv[it]);
    __syncthreads();   // drains DMA writes + A ds_writes
    // ---- compute phase: 2 k-steps of 32; 4x4 fragments per wave ----
#pragma unroll
    for (int ks = 0; ks < 2; ++ks) {
      bf16x8 af[4], bfr[4];
#pragma unroll
      for (int mi = 0; mi < 4; ++mi) {
        const int row = wr * 64 + mi * 16 + llo;
        const int ch = (ks * 4 + lhi) ^ (row & 7);
        af[mi] = *(const bf16x8*)((const char*)As + row * 128 + (ch << 4));
      }
#pragma unroll
      for (int ni = 0; ni < 4; ++ni) {
        const int row = wc * 64 + ni * 16 + llo;
        const int ch = (ks * 4 + lhi) ^ (row & 7);
        bfr[ni] = *(const bf16x8*)((const char*)Bs + row * 128 + (ch << 4));
      }
#pragma unroll
      for (int mi = 0; mi < 4; ++mi)
#pragma unroll
        for (int ni = 0; ni < 4; ++ni)
          acc[mi][ni] = __builtin_amdgcn_mfma_f32_16x16x32_bf16(af[mi], bfr[ni], acc[mi][ni], 0, 0, 0);
    }
    __syncthreads();   // all reads done before next stage overwrites
  }

  // ---- epilogue: relu(acc + Ha_i + Hv_j + bp1) . wp2 over this wave's 64 cols ----
  float hb4[4], wpv[4];
  int cg[4];
#pragma unroll
  for (int ni = 0; ni < 4; ++ni) {
    const int col = n0 + wc * 64 + ni * 16 + llo;
    cg[ni] = col;
    hb4[ni] = Ha[(size_t)i * HH + col] + bp1[col];
    wpv[ni] = wp2[col];
  }
#pragma unroll
  for (int mi = 0; mi < 4; ++mi) {
#pragma unroll
    for (int r = 0; r < 4; ++r) {
      const int rowl = wr * 64 + mi * 16 + lhi * 4 + r;
      int j = i + 1 + khalf * BM + rowl;
      if (j > MR) j = MR;
      float part = 0.f;
#pragma unroll
      for (int ni = 0; ni < 4; ++ni) {
        const float pre = acc[mi][ni][r] + hb4[ni] + Hv[(size_t)j * HH + cg[ni]];
        part += fmaxf(pre, 0.f) * wpv[ni];
      }
      part += __shfl_xor(part, 1, 64);
      part += __shfl_xor(part, 2, 64);
      part += __shfl_xor(part, 4, 64);
      part += __shfl_xor(part, 8, 64);
      if (llo == 0) redp[rowl][wc] = part;   // per-wave column-quarter partial
    }
  }
  __syncthreads();
  if (tid < BM)
    pp[(size_t)nb * NPAIR + (size_t)i * PPAD + khalf * BM + tid] =
        redp[tid][0] + redp[tid][1] + redp[tid][2] + redp[tid][3];
}

// ---------------- K5: sum partials + bias + scores, mask, softmax over 251 ----------------
__global__ __launch_bounds__(256) void softmax_kernel(
    const float* __restrict__ pp, const float* __restrict__ sfin,
    const float* __restrict__ bp2, float* __restrict__ out) {
  __shared__ float red[4];
  const int i = blockIdx.x, tid = threadIdx.x;
  float v;
  if (tid < KNUM) {
    const int jidx = i + 1 + tid;
    const bool valid = jidx < MSEL;
    const int jc = valid ? jidx : MR;
    float s = 0.f;
#pragma unroll
    for (int b = 0; b < NNB; ++b) s += pp[(size_t)b * NPAIR + i * PPAD + tid];
    v = valid ? (s + bp2[0] + sfin[jc] + sfin[i]) : -INFINITY;
  } else if (tid == KNUM) v = 0.f;
  else v = -INFINITY;
  float mx = waveMax(v);
  if ((tid & 63) == 0) red[tid >> 6] = mx;
  __syncthreads();
  const float m = fmaxf(fmaxf(red[0], red[1]), fmaxf(red[2], red[3]));
  __syncthreads();
  const float e = (tid <= KNUM) ? expf(v - m) : 0.f;
  float s = waveSum(e);
  if ((tid & 63) == 0) red[tid >> 6] = s;
  __syncthreads();
  const float tot = red[0] + red[1] + red[2] + red[3];
  if (tid <= KNUM) out[i * OUTW + tid] = e / tot;
}

extern "C" void kernel_launch(void* const* d_in, const int* in_sizes, int n_in,
                              void* d_out, int out_size, void* d_ws, size_t ws_size,
                              hipStream_t stream) {
  const float* vectors = (const float*)d_in[0];
  const float* Wm1 = (const float*)d_in[1];
  const float* bm1 = (const float*)d_in[2];
  const float* wm2 = (const float*)d_in[3];
  const float* bm2 = (const float*)d_in[4];
  const float* Wp1 = (const float*)d_in[5];
  const float* bp1 = (const float*)d_in[6];
  const float* wp2 = (const float*)d_in[7];
  const float* bp2 = (const float*)d_in[8];
  const int* sst = (const int*)d_in[9];
  const int* sen = (const int*)d_in[10];
  float* out = (float*)d_out;
  char* ws = (char*)d_ws;

  float* spart = (float*)(ws);                           // 2000*2 f32
  int*   perm  = (int*)(ws + 16384);                     // 400 i32
  float* sfin  = (float*)(ws + 18432);                   // 400 f32
  float* Ha    = (float*)(ws + 20480);                   // 400*1024 f32
  float* Hv    = (float*)(ws + 1658880);                 // 400*1024 f32
  float* Vp    = (float*)(ws + 3297280);                 // 400*768 f32
  ushort* Wt   = (ushort*)(ws + 4526080);                // 1024*768 bf16
  ushort* Vpb  = (ushort*)(ws + 6098944);                // 400*768 bf16
  float* pp    = (float*)(ws + 6713344);                 // 4 * 102144 f32 partials

  scores_kernel<<<dim3(125, 2), 512, 0, stream>>>(vectors, Wm1, bm1, wm2, spart);
  sortwt_kernel<<<193, 1024, 0, stream>>>(spart, sst, sen, bm2, Wp1, perm, sfin, Wt);
  hab_kernel<<<dim3(MSEL / 8, 4), 512, 0, stream>>>(vectors, Wp1, perm, Ha, Hv, Vp, Vpb);
  pair_kernel<<<dim3(PAIRBLKS, NNB), 512, 0, stream>>>(Vp, Vpb, Wt, bp1, wp2, Ha, Hv, pp);
  softmax_kernel<<<MR, 256, 0, stream>>>(pp, sfin, bp2, out);
}

// Round 22
// 357.312 us; speedup vs baseline: 1.2579x; 1.0421x over previous
//
#include <hip/hip_runtime.h>
#include <hip/hip_bf16.h>
#include <math.h>

#define NVEC 2000
#define DD   768
#define HH   1024
#define KNUM 250
#define MSEL 400
#define MR   399     // m-1 rows
#define OUTW 251
#define PPAD 256                 // padded antecedents per anaphor
#define NPAIR (MR * PPAD)        // 102144 padded pair rows
#define BM 128
#define BN 256
#define BK 64
#define NKT (DD / BK)            // 12
#define NNB (HH / BN)            // 4
#define KH1 271                  // khalf=1 blocks exist only for i < 271 (else fully masked)
#define PAIRBLKS (MR + KH1)      // 670

typedef short  bf16x8 __attribute__((ext_vector_type(8)));
typedef float  f32x4  __attribute__((ext_vector_type(4)));
typedef unsigned int u32;
typedef u32    u32x4  __attribute__((ext_vector_type(4)));

__device__ __forceinline__ float waveSum(float p) {
#pragma unroll
  for (int off = 32; off >= 1; off >>= 1) p += __shfl_xor(p, off, 64);
  return p;
}
__device__ __forceinline__ float waveMax(float p) {
#pragma unroll
  for (int off = 32; off >= 1; off >>= 1) p = fmaxf(p, __shfl_xor(p, off, 64));
  return p;
}
__device__ __forceinline__ short f2bf(float f) {
  __hip_bfloat16 h = __float2bfloat16(f);     // RNE; pairs fuse to v_cvt_pk_bf16_f32
  return __builtin_bit_cast(short, h);
}
__device__ __forceinline__ void gload_lds16(const void* g, void* l) {
  __builtin_amdgcn_global_load_lds(
      (const __attribute__((address_space(1))) u32*)g,
      (__attribute__((address_space(3))) u32*)l, 16, 0, 0);
}
// x[e] = bf16( av[e] * f32(b[e]) )  -- 8-element chunk, in registers
__device__ __forceinline__ bf16x8 prodcvt(const float* av, bf16x8 b) {
  u32x4 u = __builtin_bit_cast(u32x4, b);
  bf16x8 r;
#pragma unroll
  for (int p = 0; p < 4; ++p) {
    const float blo = __builtin_bit_cast(float, u[p] << 16);
    const float bhi = __builtin_bit_cast(float, u[p] & 0xffff0000u);
    r[2 * p]     = f2bf(av[2 * p]     * blo);
    r[2 * p + 1] = f2bf(av[2 * p + 1] * bhi);
  }
  return r;
}

// ---------------- K1: scores = relu(V @ Wm1 + bm1) @ wm2 + bm2 (250 blocks) ----------------
__global__ __launch_bounds__(512) void scores_kernel(
    const float* __restrict__ vectors, const float* __restrict__ Wm1,
    const float* __restrict__ bm1, const float* __restrict__ wm2,
    const float* __restrict__ bm2, float* __restrict__ scores) {
  __shared__ float vrow[8 * DD];
  __shared__ float red[8];
  const int tid = threadIdx.x;
  const int base = blockIdx.x * 8;
  for (int idx = tid; idx < 8 * DD; idx += 512)
    vrow[idx] = vectors[base * DD + idx];
  __syncthreads();
  float acc[8][2];
#pragma unroll
  for (int r = 0; r < 8; ++r) { acc[r][0] = 0.f; acc[r][1] = 0.f; }
#pragma unroll 4
  for (int d = 0; d < DD; ++d) {
    const float2 w = ((const float2*)(Wm1 + (size_t)d * HH))[tid];
#pragma unroll
    for (int r = 0; r < 8; ++r) {
      const float a = vrow[r * DD + d];
      acc[r][0] += a * w.x; acc[r][1] += a * w.y;
    }
  }
  const float2 b = ((const float2*)bm1)[tid];
  const float2 m = ((const float2*)wm2)[tid];
  const float sc = bm2[0];
  for (int r = 0; r < 8; ++r) {
    float p = fmaxf(acc[r][0] + b.x, 0.f) * m.x + fmaxf(acc[r][1] + b.y, 0.f) * m.y;
    p = waveSum(p);
    if ((tid & 63) == 0) red[tid >> 6] = p;
    __syncthreads();
    if (tid == 0) {
      float t = red[0];
#pragma unroll
      for (int w8 = 1; w8 < 8; ++w8) t += red[w8];
      scores[base + r] = t + sc;
    }
    __syncthreads();
  }
}

// ---------------- K2 (fused): block 0 = sort+lexsort | blocks 1..192 = Wt transpose ----------------
// Sort occupies one CU; the wt tiles fill the other 255 CUs concurrently (independent work).
__global__ __launch_bounds__(1024) void sortwt_kernel(
    const float* __restrict__ scores, const int* __restrict__ sst,
    const int* __restrict__ sen, const float* __restrict__ Wp1,
    int* __restrict__ perm, float* __restrict__ sfin, ushort* __restrict__ Wt) {
  const int tid = threadIdx.x;
  if (blockIdx.x == 0) {
    __shared__ float ks[2048];
    __shared__ int   ki[2048];
    __shared__ int s_st[512], s_en[512], s_j[512];
    for (int e = tid; e < 2048; e += 1024) {
      ks[e] = (e < NVEC) ? scores[e] : -INFINITY;
      ki[e] = e;
    }
    __syncthreads();
    for (int k = 2; k <= 2048; k <<= 1) {
      for (int j = k >> 1; j > 0; j >>= 1) {
        for (int e = tid; e < 2048; e += 1024) {
          const int l = e ^ j;
          if (l > e) {
            const float s1 = ks[e], s2 = ks[l];
            const int i1 = ki[e], i2 = ki[l];
            const bool first = (s1 > s2) || (s1 == s2 && i1 < i2);
            const bool up = ((e & k) == 0);
            if (up ? !first : first) {
              ks[e] = s2; ks[l] = s1; ki[e] = i2; ki[l] = i1;
            }
          }
        }
        __syncthreads();
      }
    }
    for (int e = tid; e < 512; e += 1024) {
      if (e < MSEL) { const int ti = ki[e]; s_st[e] = sst[ti]; s_en[e] = sen[ti]; }
      else { s_st[e] = 0x7fffffff; s_en[e] = 0x7fffffff; }
      s_j[e] = e;
    }
    __syncthreads();
    for (int k = 2; k <= 512; k <<= 1) {
      for (int j = k >> 1; j > 0; j >>= 1) {
        for (int e = tid; e < 512; e += 1024) {
          const int l = e ^ j;
          if (l > e) {
            const int a0 = s_st[e], a1 = s_en[e], a2 = s_j[e];
            const int b0 = s_st[l], b1 = s_en[l], b2 = s_j[l];
            const bool first = (a0 < b0) || (a0 == b0 && (a1 < b1 || (a1 == b1 && a2 < b2)));
            const bool up = ((e & k) == 0);
            if (up ? !first : first) {
              s_st[e] = b0; s_en[e] = b1; s_j[e] = b2;
              s_st[l] = a0; s_en[l] = a1; s_j[l] = a2;
            }
          }
        }
        __syncthreads();
      }
    }
    for (int i = tid; i < MSEL; i += 1024) {
      const int src = s_j[MSEL - 1 - i];
      const int vi = ki[src];
      perm[i] = vi;
      sfin[i] = scores[vi];
    }
  } else {
    // ---- Wt transpose tile: Wt[n][k] = bf16(Wab[k][n]) ----
    __shared__ float tile[64][65];
    const int t2 = blockIdx.x - 1;            // 0..191
    const int kb = t2 % 12;
    const int nb = t2 / 12;
    const float* Wab = Wp1 + 2 * DD * HH;
    for (int idx = tid; idx < 64 * 64; idx += 1024) {
      const int kk = idx >> 6, nn = idx & 63;
      tile[kk][nn] = Wab[(size_t)(kb * 64 + kk) * HH + nb * 64 + nn];
    }
    __syncthreads();
    for (int idx = tid; idx < 64 * 64; idx += 1024) {
      const int nn = idx >> 6, kk = idx & 63;
      Wt[(size_t)(nb * 64 + nn) * DD + kb * 64 + kk] = (ushort)f2bf(tile[kk][nn]);
    }
  }
}

// ---------------- K3: Ha = v@Wa, Hv = v@Wb; gather Vp (f32) + Vpb (bf16) ----------------
// 512 threads (8 waves -> 2 waves/SIMD for latency hiding), 1 scalar col/thread.
__global__ __launch_bounds__(512) void hab_kernel(
    const float* __restrict__ vectors, const float* __restrict__ Wp1,
    const int* __restrict__ perm, float* __restrict__ Ha, float* __restrict__ Hv,
    float* __restrict__ Vp, ushort* __restrict__ Vpb) {
  __shared__ float vrow[8 * DD];
  const int tid = threadIdx.x;
  const int base = blockIdx.x * 8;
  const int mat = blockIdx.y >> 1;       // 0 = Wa, 1 = Wb
  const int half = blockIdx.y & 1;       // col half
  for (int r = 0; r < 8; ++r) {
    const int pi = perm[base + r];
    for (int d = tid; d < DD; d += 512) {
      const float val = vectors[pi * DD + d];
      vrow[r * DD + d] = val;
      if (blockIdx.y == 0) {
        Vp[(size_t)(base + r) * DD + d] = val;
        Vpb[(size_t)(base + r) * DD + d] = (ushort)f2bf(val);
      }
    }
  }
  __syncthreads();
  float acc[8];
#pragma unroll
  for (int r = 0; r < 8; ++r) acc[r] = 0.f;
  const float* W = Wp1 + (size_t)mat * DD * HH + half * 512 + tid;
#pragma unroll 4
  for (int d = 0; d < DD; ++d) {
    const float w = W[(size_t)d * HH];
#pragma unroll
    for (int r = 0; r < 8; ++r) acc[r] += vrow[r * DD + d] * w;
  }
  float* dst = mat ? Hv : Ha;
  for (int r = 0; r < 8; ++r) {
    const int row = base + r;
    if (mat == 0 && row >= MR) continue;
    dst[(size_t)row * HH + half * 512 + tid] = acc[r];
  }
}

// ---------------- K4: pairwise einsum GEMM, 128x256 tile; dead khalf=1 blocks removed ----------------
__global__ __launch_bounds__(512, 2) void pair_kernel(
    const float* __restrict__ Vp, const ushort* __restrict__ Vpb,
    const ushort* __restrict__ Wt,
    const float* __restrict__ bp1, const float* __restrict__ wp2,
    const float* __restrict__ Ha, const float* __restrict__ Hv,
    float* __restrict__ pp) {
  __shared__ __align__(16) ushort As[BM * BK];      // 16 KB
  __shared__ __align__(16) ushort Bs[BN * BK];      // 32 KB
  __shared__ float redp[BM][4];                     // 2 KB
  const int tid = threadIdx.x;
  const int bx = blockIdx.x;          // 0..669
  const int khalf = (bx < MR) ? 0 : 1;
  const int i = (bx < MR) ? bx : (bx - MR);
  const int nb = blockIdx.y;          // 0..3
  const int n0 = nb * BN;
  const int lane = tid & 63;
  const int wid = tid >> 6;           // 0..7
  const int wr = wid >> 2, wc = wid & 3;
  const int lhi = lane >> 4, llo = lane & 15;

  // ---- stage geometry ----
  const int cs = tid & 7;
  const int rb9 = tid >> 3;                   // 0..63
  const int csx = cs ^ (rb9 & 7);             // same for both A chunks
  const ushort* vsrc[2];
  int rowA[2];
#pragma unroll
  for (int it = 0; it < 2; ++it) {
    rowA[it] = it * 64 + rb9;                 // 0..127
    int j = i + 1 + khalf * BM + rowA[it];
    if (j > MR) j = MR;
    vsrc[it] = Vpb + (size_t)j * DD + cs * 8;
  }
  int rowB[4];
#pragma unroll
  for (int it = 0; it < 4; ++it) rowB[it] = it * 64 + rb9;   // 0..255
  const float* avp = Vp + (size_t)i * DD + cs * 8;   // L1-hot row i

  f32x4 acc[4][4];
#pragma unroll
  for (int a = 0; a < 4; ++a)
#pragma unroll
    for (int b = 0; b < 4; ++b) acc[a][b] = (f32x4){0.f, 0.f, 0.f, 0.f};

  for (int kt = 0; kt < NKT; ++kt) {
    const int kg = kt * BK;
    // ---- stage phase: A-src loads FIRST (oldest VMEM), then B-DMAs, then prodcvt ----
    bf16x8 bv[2];
    float av[8];
#pragma unroll
    for (int it = 0; it < 2; ++it) bv[it] = *(const bf16x8*)(vsrc[it] + kg);
    *(float4*)(av) = *(const float4*)(avp + kg);
    *(float4*)(av + 4) = *(const float4*)(avp + kg + 4);
#pragma unroll
    for (int it = 0; it < 4; ++it)
      gload_lds16(Wt + (size_t)(n0 + rowB[it]) * DD + kg + csx * 8,
                  (char*)Bs + (it * 512 + tid) * 16);
#pragma unroll
    for (int it = 0; it < 2; ++it)
      *(bf16x8*)((char*)As + rowA[it] * 128 + (csx << 4)) = prodcvt(av, bv[it]);
    __syncthreads();   // drains DMA writes + A ds_writes
    // ---- compute phase: 2 k-steps of 32; 4x4 fragments per wave ----
#pragma unroll
    for (int ks = 0; ks < 2; ++ks) {
      bf16x8 af[4], bfr[4];
#pragma unroll
      for (int mi = 0; mi < 4; ++mi) {
        const int row = wr * 64 + mi * 16 + llo;
        const int ch = (ks * 4 + lhi) ^ (row & 7);
        af[mi] = *(const bf16x8*)((const char*)As + row * 128 + (ch << 4));
      }
#pragma unroll
      for (int ni = 0; ni < 4; ++ni) {
        const int row = wc * 64 + ni * 16 + llo;
        const int ch = (ks * 4 + lhi) ^ (row & 7);
        bfr[ni] = *(const bf16x8*)((const char*)Bs + row * 128 + (ch << 4));
      }
#pragma unroll
      for (int mi = 0; mi < 4; ++mi)
#pragma unroll
        for (int ni = 0; ni < 4; ++ni)
          acc[mi][ni] = __builtin_amdgcn_mfma_f32_16x16x32_bf16(af[mi], bfr[ni], acc[mi][ni], 0, 0, 0);
    }
    __syncthreads();   // all reads done before next stage overwrites
  }

  // ---- epilogue: relu(acc + Ha_i + Hv_j + bp1) . wp2 over this wave's 64 cols ----
  float hb4[4], wpv[4];
  int cg[4];
#pragma unroll
  for (int ni = 0; ni < 4; ++ni) {
    const int col = n0 + wc * 64 + ni * 16 + llo;
    cg[ni] = col;
    hb4[ni] = Ha[(size_t)i * HH + col] + bp1[col];
    wpv[ni] = wp2[col];
  }
#pragma unroll
  for (int mi = 0; mi < 4; ++mi) {
#pragma unroll
    for (int r = 0; r < 4; ++r) {
      const int rowl = wr * 64 + mi * 16 + lhi * 4 + r;
      int j = i + 1 + khalf * BM + rowl;
      if (j > MR) j = MR;
      float part = 0.f;
#pragma unroll
      for (int ni = 0; ni < 4; ++ni) {
        const float pre = acc[mi][ni][r] + hb4[ni] + Hv[(size_t)j * HH + cg[ni]];
        part += fmaxf(pre, 0.f) * wpv[ni];
      }
      part += __shfl_xor(part, 1, 64);
      part += __shfl_xor(part, 2, 64);
      part += __shfl_xor(part, 4, 64);
      part += __shfl_xor(part, 8, 64);
      if (llo == 0) redp[rowl][wc] = part;   // per-wave column-quarter partial
    }
  }
  __syncthreads();
  if (tid < BM)
    pp[(size_t)nb * NPAIR + (size_t)i * PPAD + khalf * BM + tid] =
        redp[tid][0] + redp[tid][1] + redp[tid][2] + redp[tid][3];
}

// ---------------- K5: sum partials + bias + scores, mask, softmax over 251 ----------------
__global__ __launch_bounds__(256) void softmax_kernel(
    const float* __restrict__ pp, const float* __restrict__ sfin,
    const float* __restrict__ bp2, float* __restrict__ out) {
  __shared__ float red[4];
  const int i = blockIdx.x, tid = threadIdx.x;
  float v;
  if (tid < KNUM) {
    const int jidx = i + 1 + tid;
    const bool valid = jidx < MSEL;
    const int jc = valid ? jidx : MR;
    float s = 0.f;
#pragma unroll
    for (int b = 0; b < NNB; ++b) s += pp[(size_t)b * NPAIR + i * PPAD + tid];
    v = valid ? (s + bp2[0] + sfin[jc] + sfin[i]) : -INFINITY;
  } else if (tid == KNUM) v = 0.f;
  else v = -INFINITY;
  float mx = waveMax(v);
  if ((tid & 63) == 0) red[tid >> 6] = mx;
  __syncthreads();
  const float m = fmaxf(fmaxf(red[0], red[1]), fmaxf(red[2], red[3]));
  __syncthreads();
  const float e = (tid <= KNUM) ? expf(v - m) : 0.f;
  float s = waveSum(e);
  if ((tid & 63) == 0) red[tid >> 6] = s;
  __syncthreads();
  const float tot = red[0] + red[1] + red[2] + red[3];
  if (tid <= KNUM) out[i * OUTW + tid] = e / tot;
}

extern "C" void kernel_launch(void* const* d_in, const int* in_sizes, int n_in,
                              void* d_out, int out_size, void* d_ws, size_t ws_size,
                              hipStream_t stream) {
  const float* vectors = (const float*)d_in[0];
  const float* Wm1 = (const float*)d_in[1];
  const float* bm1 = (const float*)d_in[2];
  const float* wm2 = (const float*)d_in[3];
  const float* bm2 = (const float*)d_in[4];
  const float* Wp1 = (const float*)d_in[5];
  const float* bp1 = (const float*)d_in[6];
  const float* wp2 = (const float*)d_in[7];
  const float* bp2 = (const float*)d_in[8];
  const int* sst = (const int*)d_in[9];
  const int* sen = (const int*)d_in[10];
  float* out = (float*)d_out;
  char* ws = (char*)d_ws;

  float* scores = (float*)(ws);                          // 2000 f32
  int*   perm   = (int*)(ws + 10240);                    // 400 i32
  float* sfin   = (float*)(ws + 12288);                  // 400 f32
  float* Ha     = (float*)(ws + 16384);                  // 400*1024 f32
  float* Hv     = (float*)(ws + 16384 + 1638400);        // 400*1024 f32
  float* Vp     = (float*)(ws + 3293184);                // 400*768 f32
  ushort* Wt    = (ushort*)(ws + 4521984);               // 1024*768 bf16
  ushort* Vpb   = (ushort*)(ws + 6094848);               // 400*768 bf16
  float* pp     = (float*)(ws + 6709248);                // 4 * 102144 f32 partials

  scores_kernel<<<NVEC / 8, 512, 0, stream>>>(vectors, Wm1, bm1, wm2, bm2, scores);
  sortwt_kernel<<<193, 1024, 0, stream>>>(scores, sst, sen, Wp1, perm, sfin, Wt);
  hab_kernel<<<dim3(MSEL / 8, 4), 512, 0, stream>>>(vectors, Wp1, perm, Ha, Hv, Vp, Vpb);
  pair_kernel<<<dim3(PAIRBLKS, NNB), 512, 0, stream>>>(Vp, Vpb, Wt, bp1, wp2, Ha, Hv, pp);
  softmax_kernel<<<MR, 256, 0, stream>>>(pp, sfin, bp2, out);
}